// Round 4
// baseline (90.848 us; speedup 1.0000x reference)
//
#include <hip/hip_runtime.h>
#include <math.h>

#define NPOINTS 32768
#define NPRIMS  2048
#define BLK     256
#define PBLK    (NPOINTS / BLK)   // 128 point-blocks
#define TILE    128               // prims staged per LDS tile (4 KB)

// Robust scalar-frequency decode (2400000000 in any plausible encoding):
//   float32: word = 0x4F0F0BDC -> 2.4e9 (in range)
//   int32-wrapped / int64 low word: 0x8F0D1800 -> (float)uint = 2.4e9
//   float64: lo == 0 -> read as double
__device__ __forceinline__ float read_freq(const void* p) {
    const unsigned* w = (const unsigned*)p;
    unsigned lo = w[0];
    float ff = __uint_as_float(lo);
    if (ff >= 1.0e5f && ff <= 1.0e13f) return ff;       // float32
    if (lo != 0u) return (float)lo;                      // int32-wrap / int64 lo
    double d = *(const double*)p;                        // lo==0 -> 8-byte dtype
    if (d >= 1.0e5 && d <= 1.0e13) return (float)d;      // float64
    unsigned long long v = ((unsigned long long)w[1] << 32) | lo;
    return (float)v;                                     // int64 (hi-word path)
}

// Precise sincos for |x| <= ~2000 rad. Cody-Waite pi/2 reduction (FMA-exact
// products; residual ~1e-12*xn) + minimax polys on [-pi/4, pi/4] (~1e-7 abs).
__device__ __forceinline__ void sincos_precise(float x, float* s, float* c) {
    const float TWO_OVER_PI = 0.63661977236758134f;
    const float PIO2_HI = 1.57079637050628662109375f;
    const float PIO2_MID = -4.37113900018624283e-8f;
    float xn = rintf(x * TWO_OVER_PI);
    int q = (int)xn;
    float y = fmaf(xn, -PIO2_HI, x);
    y = fmaf(xn, -PIO2_MID, y);
    float y2 = y * y;
    float ps = y * fmaf(y2, fmaf(y2, fmaf(y2, -1.9515295891e-4f,
                                              8.3321608736e-3f),
                                  -1.6666654611e-1f), 1.0f);
    float pc = fmaf(y2 * y2, fmaf(y2, fmaf(y2, 2.443315711809948e-5f,
                                               -1.388731625493765e-3f),
                                  4.166664568298827e-2f),
                    fmaf(y2, -0.5f, 1.0f));
    int qa = q & 3;
    bool swap = (qa & 1) != 0;
    float ss = swap ? pc : ps;
    float cc = swap ? ps : pc;
    if (qa == 1 || qa == 2) cc = -cc;
    if (qa >= 2) ss = -ss;
    *s = ss; *c = cc;
}

// NS = primitive splits (grid.y); each block: 256 points x (2048/NS) prims,
// staged in 128-prim LDS tiles. DIRECT: write final PLANAR f32 result (NS==1):
// out[n] = Re, out[NPOINTS+n] = Im.
template <int NS, bool DIRECT>
__global__ __launch_bounds__(BLK) void field_kernel(
        const float* __restrict__ qp,
        const float* __restrict__ pos,
        const float* __restrict__ scl,
        const float* __restrict__ amp,
        const float* __restrict__ ph,
        const void*  __restrict__ freq_p,
        float*       __restrict__ out_or_part) {
    constexpr int PC = NPRIMS / NS;
    constexpr int NT = PC / TILE;
    __shared__ float4 sA[TILE];   // (mu_x, mu_y, mu_z, amp)
    __shared__ float4 sB[TILE];   // (1/sx^2, 1/sy^2, 1/sz^2, phase)

    const int n = blockIdx.x * BLK + threadIdx.x;
    const float x = qp[3*n+0], y = qp[3*n+1], z = qp[3*n+2];
    const float kw = 6.28318530718f * read_freq(freq_p) / 299792458.0f;

    const int split = blockIdx.y;
    float re = 0.0f, im = 0.0f;

    for (int tile = 0; tile < NT; ++tile) {
        const int pbase = split * PC + tile * TILE;
        __syncthreads();   // protect previous tile's LDS reads
        if (threadIdx.x < TILE) {
            int p = pbase + threadIdx.x;
            float sx = scl[3*p+0], sy = scl[3*p+1], sz = scl[3*p+2];
            sA[threadIdx.x] = make_float4(pos[3*p+0], pos[3*p+1], pos[3*p+2], amp[p]);
            sB[threadIdx.x] = make_float4(1.0f/(sx*sx), 1.0f/(sy*sy), 1.0f/(sz*sz), ph[p]);
        }
        __syncthreads();

        #pragma unroll 4
        for (int p = 0; p < TILE; ++p) {
            float4 a = sA[p];   // broadcast LDS reads
            float4 b = sB[p];
            float dx = x - a.x, dy = y - a.y, dz = z - a.z;
            float t0 = dx*dx, t1 = dy*dy, t2 = dz*dz;
            float maha = fmaf(t0, b.x, fmaf(t1, b.y, t2 * b.z));
            maha = fmaxf(maha, 0.0f);
            float d2 = t0 + t1 + t2;
            float r  = sqrtf(fmaxf(d2, 1e-12f));
            float wgt = a.w * __builtin_amdgcn_exp2f(maha * -0.72134752044448169f);
            float phs = fmaf(kw, r, b.w);
            float s, c;
            sincos_precise(phs, &s, &c);
            re = fmaf(wgt, c, re);
            im = fmaf(wgt, s, im);
        }
    }

    if (DIRECT) {
        out_or_part[n]           = re;   // planar: real block, then imag block
        out_or_part[NPOINTS + n] = im;
    } else {
        float2* part = (float2*)out_or_part;
        part[(size_t)split * NPOINTS + n] = make_float2(re, im);
    }
}

template <int NS>
__global__ __launch_bounds__(BLK) void reduce_kernel(const float2* __restrict__ part,
                                                     float* __restrict__ out) {
    int n = blockIdx.x * blockDim.x + threadIdx.x;
    float re = 0.0f, im = 0.0f;
    #pragma unroll
    for (int s = 0; s < NS; ++s) {
        float2 v = part[(size_t)s * NPOINTS + n];
        re += v.x; im += v.y;
    }
    out[n]           = re;   // planar layout
    out[NPOINTS + n] = im;
}

extern "C" void kernel_launch(void* const* d_in, const int* in_sizes, int n_in,
                              void* d_out, int out_size, void* d_ws, size_t ws_size,
                              hipStream_t stream) {
    const float* qp  = (const float*)d_in[0];
    const float* pos = (const float*)d_in[1];
    const float* scl = (const float*)d_in[2];
    const float* amp = (const float*)d_in[3];
    const float* ph  = (const float*)d_in[4];
    const void*  fq  = d_in[5];

    float2* partial = (float2*)d_ws;
    const size_t per_split = (size_t)NPOINTS * sizeof(float2);   // 256 KB
    float* out = (float*)d_out;

    if (ws_size >= 16 * per_split) {
        field_kernel<16, false><<<dim3(PBLK, 16), dim3(BLK), 0, stream>>>(qp, pos, scl, amp, ph, fq, (float*)partial);
        reduce_kernel<16><<<dim3(NPOINTS / BLK), dim3(BLK), 0, stream>>>(partial, out);
    } else if (ws_size >= 8 * per_split) {
        field_kernel<8, false><<<dim3(PBLK, 8), dim3(BLK), 0, stream>>>(qp, pos, scl, amp, ph, fq, (float*)partial);
        reduce_kernel<8><<<dim3(NPOINTS / BLK), dim3(BLK), 0, stream>>>(partial, out);
    } else if (ws_size >= 4 * per_split) {
        field_kernel<4, false><<<dim3(PBLK, 4), dim3(BLK), 0, stream>>>(qp, pos, scl, amp, ph, fq, (float*)partial);
        reduce_kernel<4><<<dim3(NPOINTS / BLK), dim3(BLK), 0, stream>>>(partial, out);
    } else if (ws_size >= 2 * per_split) {
        field_kernel<2, false><<<dim3(PBLK, 2), dim3(BLK), 0, stream>>>(qp, pos, scl, amp, ph, fq, (float*)partial);
        reduce_kernel<2><<<dim3(NPOINTS / BLK), dim3(BLK), 0, stream>>>(partial, out);
    } else {
        field_kernel<1, true><<<dim3(PBLK, 1), dim3(BLK), 0, stream>>>(qp, pos, scl, amp, ph, fq, out);
    }
}

// Round 5
// 47.341 us; speedup vs baseline: 1.9190x; 1.9190x over previous
//
#include <hip/hip_runtime.h>
#include <math.h>

#define NPOINTS 32768
#define NPRIMS  2048
#define BLK     256
#define PBLK    (NPOINTS / BLK)   // 128 point-blocks
#define TILE    128               // prims staged per LDS tile (4 KB)

// Robust scalar-frequency decode (2400000000 in any plausible encoding).
__device__ __forceinline__ float read_freq(const void* p) {
    const unsigned* w = (const unsigned*)p;
    unsigned lo = w[0];
    float ff = __uint_as_float(lo);
    if (ff >= 1.0e5f && ff <= 1.0e13f) return ff;       // float32
    if (lo != 0u) return (float)lo;                      // int32-wrap / int64 lo
    double d = *(const double*)p;                        // lo==0 -> 8-byte dtype
    if (d >= 1.0e5 && d <= 1.0e13) return (float)d;      // float64
    unsigned long long v = ((unsigned long long)w[1] << 32) | lo;
    return (float)v;                                     // int64 (hi-word path)
}

// NS = primitive splits (grid.y); each block: 256 points x (2048/NS) prims,
// staged in 128-prim LDS tiles. Staged values are pre-folded:
//   sA = (mu_x, mu_y, mu_z, amp)
//   sB = (ivx*KE, ivy*KE, ivz*KE, phase/(2*pi))   KE = -0.5*log2(e)
// so the envelope is amp*exp2(fma-chain) and the propagation phase is
// fract(kr*r + phrev) in revolutions, feeding v_sin/v_cos directly.
// DIRECT: write final PLANAR f32 result (out[n]=Re, out[NPOINTS+n]=Im).
template <int NS, bool DIRECT>
__global__ __launch_bounds__(BLK) void field_kernel(
        const float* __restrict__ qp,
        const float* __restrict__ pos,
        const float* __restrict__ scl,
        const float* __restrict__ amp,
        const float* __restrict__ ph,
        const void*  __restrict__ freq_p,
        float*       __restrict__ out_or_part) {
    constexpr int PC = NPRIMS / NS;
    constexpr int NT = PC / TILE;
    __shared__ float4 sA[TILE];
    __shared__ float4 sB[TILE];

    const int n = blockIdx.x * BLK + threadIdx.x;
    const float x = qp[3*n+0], y = qp[3*n+1], z = qp[3*n+2];
    // kr = f/c  (cycles per metre; phase tracked in revolutions)
    const float kr = read_freq(freq_p) / 299792458.0f;

    const int split = blockIdx.y;
    float re = 0.0f, im = 0.0f;

    const float KE     = -0.72134752044448169f;   // -0.5*log2(e)
    const float INV2PI =  0.15915494309189535f;

    for (int tile = 0; tile < NT; ++tile) {
        const int pbase = split * PC + tile * TILE;
        __syncthreads();   // protect previous tile's LDS reads
        if (threadIdx.x < TILE) {
            int p = pbase + threadIdx.x;
            float sx = scl[3*p+0], sy = scl[3*p+1], sz = scl[3*p+2];
            sA[threadIdx.x] = make_float4(pos[3*p+0], pos[3*p+1], pos[3*p+2], amp[p]);
            sB[threadIdx.x] = make_float4(KE * __builtin_amdgcn_rcpf(sx*sx),
                                          KE * __builtin_amdgcn_rcpf(sy*sy),
                                          KE * __builtin_amdgcn_rcpf(sz*sz),
                                          ph[p] * INV2PI);
        }
        __syncthreads();

        #pragma unroll 8
        for (int p = 0; p < TILE; ++p) {
            float4 a = sA[p];   // broadcast LDS reads (wave-uniform addr)
            float4 b = sB[p];
            float dx = x - a.x, dy = y - a.y, dz = z - a.z;
            float t0 = dx*dx, t1 = dy*dy, t2 = dz*dz;
            float e  = fmaf(t0, b.x, fmaf(t1, b.y, t2 * b.z));   // <= 0
            float d2 = t0 + t1 + t2;
            float r  = __builtin_amdgcn_sqrtf(fmaxf(d2, 1e-12f));
            float w  = a.w * __builtin_amdgcn_exp2f(e);
            float tp = __builtin_amdgcn_fractf(fmaf(kr, r, b.w));
            float s  = __builtin_amdgcn_sinf(tp);
            float c  = __builtin_amdgcn_cosf(tp);
            re = fmaf(w, c, re);
            im = fmaf(w, s, im);
        }
    }

    if (DIRECT) {
        out_or_part[n]           = re;   // planar: real block then imag block
        out_or_part[NPOINTS + n] = im;
    } else {
        float2* part = (float2*)out_or_part;
        part[(size_t)split * NPOINTS + n] = make_float2(re, im);
    }
}

template <int NS>
__global__ __launch_bounds__(BLK) void reduce_kernel(const float2* __restrict__ part,
                                                     float* __restrict__ out) {
    int n = blockIdx.x * blockDim.x + threadIdx.x;
    float re = 0.0f, im = 0.0f;
    #pragma unroll
    for (int s = 0; s < NS; ++s) {
        float2 v = part[(size_t)s * NPOINTS + n];
        re += v.x; im += v.y;
    }
    out[n]           = re;   // planar layout
    out[NPOINTS + n] = im;
}

extern "C" void kernel_launch(void* const* d_in, const int* in_sizes, int n_in,
                              void* d_out, int out_size, void* d_ws, size_t ws_size,
                              hipStream_t stream) {
    const float* qp  = (const float*)d_in[0];
    const float* pos = (const float*)d_in[1];
    const float* scl = (const float*)d_in[2];
    const float* amp = (const float*)d_in[3];
    const float* ph  = (const float*)d_in[4];
    const void*  fq  = d_in[5];

    float2* partial = (float2*)d_ws;
    const size_t per_split = (size_t)NPOINTS * sizeof(float2);   // 256 KB
    float* out = (float*)d_out;

    if (ws_size >= 16 * per_split) {
        field_kernel<16, false><<<dim3(PBLK, 16), dim3(BLK), 0, stream>>>(qp, pos, scl, amp, ph, fq, (float*)partial);
        reduce_kernel<16><<<dim3(NPOINTS / BLK), dim3(BLK), 0, stream>>>(partial, out);
    } else if (ws_size >= 8 * per_split) {
        field_kernel<8, false><<<dim3(PBLK, 8), dim3(BLK), 0, stream>>>(qp, pos, scl, amp, ph, fq, (float*)partial);
        reduce_kernel<8><<<dim3(NPOINTS / BLK), dim3(BLK), 0, stream>>>(partial, out);
    } else if (ws_size >= 4 * per_split) {
        field_kernel<4, false><<<dim3(PBLK, 4), dim3(BLK), 0, stream>>>(qp, pos, scl, amp, ph, fq, (float*)partial);
        reduce_kernel<4><<<dim3(NPOINTS / BLK), dim3(BLK), 0, stream>>>(partial, out);
    } else if (ws_size >= 2 * per_split) {
        field_kernel<2, false><<<dim3(PBLK, 2), dim3(BLK), 0, stream>>>(qp, pos, scl, amp, ph, fq, (float*)partial);
        reduce_kernel<2><<<dim3(NPOINTS / BLK), dim3(BLK), 0, stream>>>(partial, out);
    } else {
        field_kernel<1, true><<<dim3(PBLK, 1), dim3(BLK), 0, stream>>>(qp, pos, scl, amp, ph, fq, out);
    }
}

// Round 6
// 47.275 us; speedup vs baseline: 1.9217x; 1.0014x over previous
//
#include <hip/hip_runtime.h>
#include <math.h>

#define NPOINTS 32768
#define NPRIMS  2048
#define BLK     256
#define PBLK    (NPOINTS / BLK)   // 128 point-blocks
#define NSPLIT  16                // primitive splits (grid.y)

typedef float v2f __attribute__((ext_vector_type(2)));

// 64-byte packed record for a pair of primitives (SoA-in-pairs):
//  q0 = (mux0, mux1, muy0, muy1)
//  q1 = (muz0, muz1, amp0, amp1)
//  q2 = (gx0,  gx1,  gy0,  gy1 )   g = -0.5*log2(e)/s^2
//  q3 = (gz0,  gz1,  ph0,  ph1 )   ph in revolutions (phase/2pi)
struct PrimPair { float4 q0, q1, q2, q3; };

// Robust scalar-frequency decode (2400000000 in any plausible encoding).
__device__ __forceinline__ float read_freq(const void* p) {
    const unsigned* w = (const unsigned*)p;
    unsigned lo = w[0];
    float ff = __uint_as_float(lo);
    if (ff >= 1.0e5f && ff <= 1.0e13f) return ff;       // float32
    if (lo != 0u) return (float)lo;                      // int32-wrap / int64 lo
    double d = *(const double*)p;                        // lo==0 -> 8-byte dtype
    if (d >= 1.0e5 && d <= 1.0e13) return (float)d;      // float64
    unsigned long long v = ((unsigned long long)w[1] << 32) | lo;
    return (float)v;                                     // int64 (hi-word path)
}

__global__ __launch_bounds__(BLK) void prep_kernel(
        const float* __restrict__ pos,
        const float* __restrict__ scl,
        const float* __restrict__ amp,
        const float* __restrict__ ph,
        PrimPair* __restrict__ pp) {
    int j = blockIdx.x * blockDim.x + threadIdx.x;
    if (j >= NPRIMS / 2) return;
    const float KE     = -0.72134752044448169f;   // -0.5*log2(e)
    const float INV2PI =  0.15915494309189535f;
    int p0 = 2 * j, p1 = 2 * j + 1;
    float s0x = scl[3*p0+0], s0y = scl[3*p0+1], s0z = scl[3*p0+2];
    float s1x = scl[3*p1+0], s1y = scl[3*p1+1], s1z = scl[3*p1+2];
    PrimPair P;
    P.q0 = make_float4(pos[3*p0+0], pos[3*p1+0], pos[3*p0+1], pos[3*p1+1]);
    P.q1 = make_float4(pos[3*p0+2], pos[3*p1+2], amp[p0], amp[p1]);
    P.q2 = make_float4(KE / (s0x*s0x), KE / (s1x*s1x), KE / (s0y*s0y), KE / (s1y*s1y));
    P.q3 = make_float4(KE / (s0z*s0z), KE / (s1z*s1z), ph[p0] * INV2PI, ph[p1] * INV2PI);
    pp[j] = P;
}

// Each block: 256 points x (NPRIMS/NSPLIT = 128) prims = 64 packed pairs.
// Prim data arrives via wave-uniform s_load (scalar pipe); all per-pair math
// in packed fp32 (v_pk_*); only sqrt/exp2/sin/cos are per-half scalar trans.
__global__ __launch_bounds__(BLK) void field_kernel(
        const float* __restrict__ qp,
        const PrimPair* __restrict__ pp,
        const void* __restrict__ freq_p,
        float2* __restrict__ part) {
    const int n = blockIdx.x * BLK + threadIdx.x;
    const float x = qp[3*n+0], y = qp[3*n+1], z = qp[3*n+2];
    const float kr = read_freq(freq_p) / 299792458.0f;   // cycles per metre

    constexpr int PAIRS = (NPRIMS / NSPLIT) / 2;   // 64
    const int base = blockIdx.y * PAIRS;

    v2f re = {0.0f, 0.0f}, im = {0.0f, 0.0f};
    const v2f xx = {x, x}, yy = {y, y}, zz = {z, z};
    const v2f kr2 = {kr, kr};
    const v2f eps2 = {1e-12f, 1e-12f};

    #pragma unroll 4
    for (int j = 0; j < PAIRS; ++j) {
        PrimPair P = pp[base + j];                 // wave-uniform -> s_load
        v2f mux = {P.q0.x, P.q0.y}, muy = {P.q0.z, P.q0.w};
        v2f muz = {P.q1.x, P.q1.y}, am2 = {P.q1.z, P.q1.w};
        v2f gx  = {P.q2.x, P.q2.y}, gy  = {P.q2.z, P.q2.w};
        v2f gz  = {P.q3.x, P.q3.y}, ph2 = {P.q3.z, P.q3.w};

        v2f dx = xx - mux, dy = yy - muy, dz = zz - muz;
        v2f t0 = dx * dx, t1 = dy * dy, t2 = dz * dz;
        v2f e  = t0 * gx + t1 * gy + t2 * gz;      // <= 0; pk_fma chain
        v2f d2 = t0 + t1 + t2;
        d2 = __builtin_elementwise_max(d2, eps2);

        float r0 = __builtin_amdgcn_sqrtf(d2.x);
        float r1 = __builtin_amdgcn_sqrtf(d2.y);
        float e0 = __builtin_amdgcn_exp2f(e.x);
        float e1 = __builtin_amdgcn_exp2f(e.y);
        v2f r2 = {r0, r1};
        v2f ex = {e0, e1};
        v2f w2 = am2 * ex;
        v2f tp = kr2 * r2 + ph2;                   // pk_fma
        float f0 = __builtin_amdgcn_fractf(tp.x);
        float f1 = __builtin_amdgcn_fractf(tp.y);
        float s0 = __builtin_amdgcn_sinf(f0);
        float s1 = __builtin_amdgcn_sinf(f1);
        float c0 = __builtin_amdgcn_cosf(f0);
        float c1 = __builtin_amdgcn_cosf(f1);
        v2f s2 = {s0, s1}, c2 = {c0, c1};
        re += w2 * c2;                             // pk_fma
        im += w2 * s2;                             // pk_fma
    }

    part[(size_t)blockIdx.y * NPOINTS + n] = make_float2(re.x + re.y, im.x + im.y);
}

__global__ __launch_bounds__(BLK) void reduce_kernel(const float2* __restrict__ part,
                                                     float* __restrict__ out) {
    int n = blockIdx.x * blockDim.x + threadIdx.x;
    float re = 0.0f, im = 0.0f;
    #pragma unroll
    for (int s = 0; s < NSPLIT; ++s) {
        float2 v = part[(size_t)s * NPOINTS + n];
        re += v.x; im += v.y;
    }
    out[n]           = re;   // planar: real block then imag block
    out[NPOINTS + n] = im;
}

// Fallback (tiny workspace): round-5 style LDS kernel, single split, direct
// planar output. Only used if ws can't hold packed prims + partials.
__global__ __launch_bounds__(BLK) void field_fallback(
        const float* __restrict__ qp,
        const float* __restrict__ pos,
        const float* __restrict__ scl,
        const float* __restrict__ amp,
        const float* __restrict__ ph,
        const void*  __restrict__ freq_p,
        float*       __restrict__ out) {
    __shared__ float4 sA[128];
    __shared__ float4 sB[128];
    const int n = blockIdx.x * BLK + threadIdx.x;
    const float x = qp[3*n+0], y = qp[3*n+1], z = qp[3*n+2];
    const float kr = read_freq(freq_p) / 299792458.0f;
    const float KE = -0.72134752044448169f, INV2PI = 0.15915494309189535f;
    float re = 0.0f, im = 0.0f;
    for (int tile = 0; tile < NPRIMS / 128; ++tile) {
        __syncthreads();
        if (threadIdx.x < 128) {
            int p = tile * 128 + threadIdx.x;
            float sx = scl[3*p+0], sy = scl[3*p+1], sz = scl[3*p+2];
            sA[threadIdx.x] = make_float4(pos[3*p+0], pos[3*p+1], pos[3*p+2], amp[p]);
            sB[threadIdx.x] = make_float4(KE/(sx*sx), KE/(sy*sy), KE/(sz*sz), ph[p]*INV2PI);
        }
        __syncthreads();
        #pragma unroll 8
        for (int p = 0; p < 128; ++p) {
            float4 a = sA[p];
            float4 b = sB[p];
            float dx = x - a.x, dy = y - a.y, dz = z - a.z;
            float t0 = dx*dx, t1 = dy*dy, t2 = dz*dz;
            float e  = fmaf(t0, b.x, fmaf(t1, b.y, t2 * b.z));
            float d2 = t0 + t1 + t2;
            float r  = __builtin_amdgcn_sqrtf(fmaxf(d2, 1e-12f));
            float w  = a.w * __builtin_amdgcn_exp2f(e);
            float tp = __builtin_amdgcn_fractf(fmaf(kr, r, b.w));
            float s  = __builtin_amdgcn_sinf(tp);
            float c  = __builtin_amdgcn_cosf(tp);
            re = fmaf(w, c, re);
            im = fmaf(w, s, im);
        }
    }
    out[n]           = re;
    out[NPOINTS + n] = im;
}

extern "C" void kernel_launch(void* const* d_in, const int* in_sizes, int n_in,
                              void* d_out, int out_size, void* d_ws, size_t ws_size,
                              hipStream_t stream) {
    const float* qp  = (const float*)d_in[0];
    const float* pos = (const float*)d_in[1];
    const float* scl = (const float*)d_in[2];
    const float* amp = (const float*)d_in[3];
    const float* ph  = (const float*)d_in[4];
    const void*  fq  = d_in[5];
    float* out = (float*)d_out;

    const size_t packed_bytes = (size_t)(NPRIMS / 2) * sizeof(PrimPair);  // 64 KB
    const size_t part_bytes   = (size_t)NSPLIT * NPOINTS * sizeof(float2); // 4 MB

    if (ws_size >= packed_bytes + part_bytes) {
        PrimPair* pp   = (PrimPair*)d_ws;
        float2*   part = (float2*)((char*)d_ws + packed_bytes);
        prep_kernel<<<dim3((NPRIMS/2 + BLK - 1) / BLK), dim3(BLK), 0, stream>>>(pos, scl, amp, ph, pp);
        field_kernel<<<dim3(PBLK, NSPLIT), dim3(BLK), 0, stream>>>(qp, pp, fq, part);
        reduce_kernel<<<dim3(NPOINTS / BLK), dim3(BLK), 0, stream>>>(part, out);
    } else {
        field_fallback<<<dim3(PBLK), dim3(BLK), 0, stream>>>(qp, pos, scl, amp, ph, fq, out);
    }
}